// Round 8
// baseline (149.063 us; speedup 1.0000x reference)
//
#include <hip/hip_runtime.h>
#include <hip/hip_bf16.h>

#define BN_EPS 1e-5f

typedef short bf16x8 __attribute__((ext_vector_type(8)));
typedef float f32x4  __attribute__((ext_vector_type(4)));

static __device__ __forceinline__ unsigned short f2bf(float f) {
    union { float f; unsigned int u; } v; v.f = f;
    unsigned int u = v.u;
    unsigned int r = (u + 0x7FFFu + ((u >> 16) & 1u)) >> 16;   // round-to-nearest-even
    return (unsigned short)r;
}

// hot-path: single HW cvt (RNE)
static __device__ __forceinline__ unsigned short f2bf_hw(float f) {
    __hip_bfloat16 b = __float2bfloat16(f);
    union { __hip_bfloat16 b; unsigned short u; } v; v.b = b;
    return v.u;
}

// ---------------- fused prep kernel (unchanged) ----------------
__global__ __launch_bounds__(256) void k_prep(
        const float* __restrict__ h, unsigned short* __restrict__ hb, int n4, int nCvt,
        const float* __restrict__ W0, const float* __restrict__ b0,
        const float* __restrict__ W1, const float* __restrict__ b1,
        const float* __restrict__ W2, const float* __restrict__ b2,
        const float* __restrict__ g0, const float* __restrict__ be0,
        const float* __restrict__ m0, const float* __restrict__ v0,
        const float* __restrict__ g1, const float* __restrict__ be1,
        const float* __restrict__ m1, const float* __restrict__ v1,
        const float* __restrict__ g2, const float* __restrict__ be2,
        const float* __restrict__ m2, const float* __restrict__ v2,
        unsigned short* __restrict__ W0sw, unsigned short* __restrict__ W1sw,
        float* __restrict__ b0f, float* __restrict__ b1f,
        float* __restrict__ w2f, float* __restrict__ b2f) {
    const int b = blockIdx.x;
    const int tid = threadIdx.x;

    if (b < nCvt) {                       // ---- h -> bf16 ----
        int i = b * 256 + tid;
        if (i < n4) {
            float4 f = ((const float4*)h)[i];
            ushort4 o;
            o.x = f2bf(f.x); o.y = f2bf(f.y); o.z = f2bf(f.z); o.w = f2bf(f.w);
            ((ushort4*)hb)[i] = o;
        }
        return;
    }
    int br = b - nCvt;
    if (br < 128) {                        // ---- W0sw ----
        int t = br * 256 + tid;
        int j = t & 7, lane = (t >> 3) & 63, nt = (t >> 9) & 7, kb = t >> 12;
        int k = kb * 32 + (lane >> 4) * 8 + j;
        int n = nt * 16 + (lane & 15);
        float s = g0[k] * rsqrtf(v0[k] + BN_EPS);
        W0sw[t] = f2bf(W0[n * 256 + k] * s);
        return;
    }
    br -= 128;
    if (br < 64) {                         // ---- W1sw ----
        int t = br * 256 + tid;
        int j = t & 7, lane = (t >> 3) & 63, nt = (t >> 9) & 7, kb = t >> 12;
        int k = kb * 32 + (lane >> 4) * 8 + j;
        int n = nt * 16 + (lane & 15);
        float s = g1[k] * rsqrtf(v1[k] + BN_EPS);
        W1sw[t] = f2bf(W1[n * 128 + k] * s);
        return;
    }
    br -= 64;
    {                                      // ---- folded biases (row = br) ----
        if (tid >= 64) return;
        const int i = br, lane = tid;
        float s0 = 0.f;
#pragma unroll
        for (int c = 0; c < 4; c++) {
            int k = c * 64 + lane;
            float sc = g0[k] * rsqrtf(v0[k] + BN_EPS);
            s0 += W0[i * 256 + k] * (be0[k] - m0[k] * sc);
        }
        float s1 = 0.f;
#pragma unroll
        for (int c = 0; c < 2; c++) {
            int k = c * 64 + lane;
            float sc = g1[k] * rsqrtf(v1[k] + BN_EPS);
            s1 += W1[i * 128 + k] * (be1[k] - m1[k] * sc);
        }
        float s2 = 0.f;
        if (i == 0) {
#pragma unroll
            for (int c = 0; c < 2; c++) {
                int k = c * 64 + lane;
                float sc = g2[k] * rsqrtf(v2[k] + BN_EPS);
                s2 += W2[k] * (be2[k] - m2[k] * sc);
            }
        }
#pragma unroll
        for (int off = 1; off < 64; off <<= 1) {
            s0 += __shfl_xor(s0, off);
            s1 += __shfl_xor(s1, off);
            s2 += __shfl_xor(s2, off);
        }
        if (lane == 0) {
            b0f[i] = b0[i] + s0;
            b1f[i] = b1[i] + s1;
            w2f[i] = W2[i] * (g2[i] * rsqrtf(v2[i] + BN_EPS));
            if (i == 0) b2f[0] = b2[0] + s2;
        }
    }
}

// ---------------- main kernel: R5 structure, M6 groups (96 edges) ----------------
// Block = 4 waves, 96 edges/group (6 m-groups of 16), grid-stride, 2 blocks/CU
// (LDS 72 KB, regs ~190 < 256 — NO spill; the (256,3) experiments R6/R7 proved
// 3/CU unreachable without scratch traffic). Wave w owns n-slice [32w,32w+32),
// B0+B1 persistent in regs. A gathered by global_load_lds: wave w issues the
// g=w chunks; waves 0,1 also issue g=4+w. 2 barriers per 96 edges (was per 64).
// Direct float4 stores from stage 2 (no pS round-trip).
__global__ __launch_bounds__(256, 2) void k_main(
        const int* __restrict__ src, const int* __restrict__ dst,
        const unsigned short* __restrict__ hb,
        const unsigned short* __restrict__ W0sw, const unsigned short* __restrict__ W1sw,
        const float* __restrict__ b0f, const float* __restrict__ b1f,
        const float* __restrict__ w2f, const float* __restrict__ b2fp,
        float* __restrict__ out, int E, int nGroups) {
    // A: [g(6)][half(2)][kb4(4)][lane(64)][8 bf16] = 48 KB
    __shared__ __align__(16) unsigned short Abuf[6 * 2 * 4 * 64 * 8];
    __shared__ __align__(16) unsigned short x1S[6][4][64][8];   // 24 KB

    const int tid  = threadIdx.x;
    const int wave = tid >> 6;
    const int lane = tid & 63;
    const int quad = lane >> 4;
    const int m    = lane & 15;

    // ---- persistent weight fragments (nt = 2*wave + hh) ----
    bf16x8 B0[8][2], B1[4][2];
#pragma unroll
    for (int kb = 0; kb < 8; kb++)
#pragma unroll
        for (int hh = 0; hh < 2; hh++)
            B0[kb][hh] = *(const bf16x8*)(W0sw + ((kb * 8 + (wave * 2 + hh)) * 64 + lane) * 8);
#pragma unroll
    for (int kb = 0; kb < 4; kb++)
#pragma unroll
        for (int hh = 0; hh < 2; hh++)
            B1[kb][hh] = *(const bf16x8*)(W1sw + ((kb * 8 + (wave * 2 + hh)) * 64 + lane) * 8);

    float b0v[2], b1v[2], w2v[2];
#pragma unroll
    for (int hh = 0; hh < 2; hh++) {
        int n = (wave * 2 + hh) * 16 + m;
        b0v[hh] = b0f[n];
        b1v[hh] = b1f[n];
        w2v[hh] = w2f[n];
    }
    const float b2s = *b2fp;
    const int stride = gridDim.x;

    // DMA ownership: wave w gathers g = w; waves 0,1 additionally g = 4 + w.
    const int nMyG = (wave < 2) ? 2 : 1;
    int myG0 = wave, myG1 = 4 + wave;

    // ---- prologue: gather group blockIdx.x ----
    int gi = blockIdx.x;
    int rS0, rD0, rS1, rD1;
    {
        int e0 = gi * 96 + myG0 * 16 + m;
        if (e0 >= E) e0 = E - 1;
        rS0 = src[e0]; rD0 = dst[e0];
        if (nMyG == 2) {
            int e1 = gi * 96 + myG1 * 16 + m;
            if (e1 >= E) e1 = E - 1;
            rS1 = src[e1]; rD1 = dst[e1];
        }
#pragma unroll
        for (int idx = 0; idx < 2; idx++) {
            if (idx >= nMyG) break;
            int g  = idx ? myG1 : myG0;
            int rs = idx ? rS1 : rS0;
            int rd = idx ? rD1 : rD0;
#pragma unroll
            for (int half = 0; half < 2; half++) {
                int row = half ? rd : rs;
#pragma unroll
                for (int kb4 = 0; kb4 < 4; kb4++) {
                    const unsigned short* gp = hb + (size_t)row * 128 + kb4 * 32 + quad * 8;
                    unsigned short* lp = Abuf + ((g * 2 + half) * 4 + kb4) * 512 + lane * 8;
                    __builtin_amdgcn_global_load_lds(
                        (const __attribute__((address_space(1))) void*)gp,
                        (__attribute__((address_space(3))) void*)lp, 16, 0, 0);
                }
            }
        }
    }

    for (; gi < nGroups; gi += stride) {
        const int eBase = gi * 96;
        __syncthreads();   // (a) own DMA retired -> Abuf[gi] fully visible

        // prefetch next group's indices (latency hidden under stage0)
        int nextGi = gi + stride;
        {
            int eb = (nextGi < nGroups ? nextGi : gi) * 96;
            int e0 = eb + myG0 * 16 + m;
            if (e0 >= E) e0 = E - 1;
            rS0 = src[e0]; rD0 = dst[e0];
            if (nMyG == 2) {
                int e1 = eb + myG1 * 16 + m;
                if (e1 >= E) e1 = E - 1;
                rS1 = src[e1]; rD1 = dst[e1];
            }
        }

        // ---- stage 0: [96 x 256] @ W0slice ----
        f32x4 acc0[6][2];
#pragma unroll
        for (int g = 0; g < 6; g++)
#pragma unroll
            for (int hh = 0; hh < 2; hh++) acc0[g][hh] = (f32x4){0.f, 0.f, 0.f, 0.f};

#pragma unroll
        for (int kb = 0; kb < 8; kb++) {
            bf16x8 a[6];
#pragma unroll
            for (int g = 0; g < 6; g++)
                a[g] = *(const bf16x8*)(Abuf + ((g * 2 + (kb >> 2)) * 4 + (kb & 3)) * 512 + lane * 8);
#pragma unroll
            for (int hh = 0; hh < 2; hh++)
#pragma unroll
                for (int g = 0; g < 6; g++)
                    acc0[g][hh] = __builtin_amdgcn_mfma_f32_16x16x32_bf16(a[g], B0[kb][hh], acc0[g][hh], 0, 0, 0);
        }

        // ---- epilogue 0: relu -> x1S (wave w writes kb1 = w slice) ----
#pragma unroll
        for (int g = 0; g < 6; g++) {
#pragma unroll
            for (int hh = 0; hh < 2; hh++) {
                int qp = (hh << 1) | (m >> 3);
                int j  = m & 7;
#pragma unroll
                for (int r = 0; r < 4; r++) {
                    float v = acc0[g][hh][r] + b0v[hh];
                    v = v > 0.f ? v : 0.f;
                    x1S[g][wave][qp * 16 + quad * 4 + r][j] = f2bf_hw(v);
                }
            }
        }
        __syncthreads();   // (b) x1 visible; stage-0 A reads done (Abuf reusable)

        // ---- issue next group's DMA gather ----
        if (nextGi < nGroups) {
#pragma unroll
            for (int idx = 0; idx < 2; idx++) {
                if (idx >= nMyG) break;
                int g  = idx ? myG1 : myG0;
                int rs = idx ? rS1 : rS0;
                int rd = idx ? rD1 : rD0;
#pragma unroll
                for (int half = 0; half < 2; half++) {
                    int row = half ? rd : rs;
#pragma unroll
                    for (int kb4 = 0; kb4 < 4; kb4++) {
                        const unsigned short* gp = hb + (size_t)row * 128 + kb4 * 32 + quad * 8;
                        unsigned short* lp = Abuf + ((g * 2 + half) * 4 + kb4) * 512 + lane * 8;
                        __builtin_amdgcn_global_load_lds(
                            (const __attribute__((address_space(1))) void*)gp,
                            (__attribute__((address_space(3))) void*)lp, 16, 0, 0);
                    }
                }
            }
        }

        // ---- stage 1: [96 x 128] @ W1slice ----
        f32x4 acc1[6][2];
#pragma unroll
        for (int g = 0; g < 6; g++)
#pragma unroll
            for (int hh = 0; hh < 2; hh++) acc1[g][hh] = (f32x4){0.f, 0.f, 0.f, 0.f};

#pragma unroll
        for (int kb = 0; kb < 4; kb++) {
            bf16x8 a[6];
#pragma unroll
            for (int g = 0; g < 6; g++)
                a[g] = *(const bf16x8*)&x1S[g][kb][lane][0];
#pragma unroll
            for (int hh = 0; hh < 2; hh++)
#pragma unroll
                for (int g = 0; g < 6; g++)
                    acc1[g][hh] = __builtin_amdgcn_mfma_f32_16x16x32_bf16(a[g], B1[kb][hh], acc1[g][hh], 0, 0, 0);
        }

        // ---- stage 2: partial dot over this wave's 32 n, 16-lane reduce, store ----
#pragma unroll
        for (int g = 0; g < 6; g++) {
            float s[4] = {0.f, 0.f, 0.f, 0.f};
#pragma unroll
            for (int hh = 0; hh < 2; hh++)
#pragma unroll
                for (int r = 0; r < 4; r++) {
                    float v = acc1[g][hh][r] + b1v[hh];
                    v = v > 0.f ? v : 0.f;
                    s[r] += v * w2v[hh];
                }
            // reduce across 16 m-lanes (partials over n within this wave)...
#pragma unroll
            for (int off = 1; off < 16; off <<= 1)
#pragma unroll
                for (int r = 0; r < 4; r++) s[r] += __shfl_xor(s[r], off, 16);
            // ...then waves hold partials over disjoint n-slices: accumulate via LDS-free
            // cross-wave? No — n-split partials live in different waves. Use atomics-free
            // scheme: each wave adds its partial into out via one wave doing the sum.
            // Simplest correct: wave-partials exchanged through x1S (dead after stage 1).
            if (m == 0) {
                float* pS = (float*)&x1S[0][0][0][0];   // alias: x1S dead until next epoch's epilogue
                pS[(wave * 6 + g) * 16 + quad * 4 + 0] = s[0];
                pS[(wave * 6 + g) * 16 + quad * 4 + 1] = s[1];
                pS[(wave * 6 + g) * 16 + quad * 4 + 2] = s[2];
                pS[(wave * 6 + g) * 16 + quad * 4 + 3] = s[3];
            }
        }
        __syncthreads();   // (c) partials visible; also gates x1S reuse next iter
        {
            // 96 outputs, lanes 0..95 of waves 0,1 store one edge each
            int eo = wave * 64 + lane;          // 0..127
            if (wave < 2 && eo < 96) {
                const float* pS = (const float*)&x1S[0][0][0][0];
                int e = eBase + eo;
                if (e < E)
                    out[e] = pS[0 * 96 + eo] + pS[1 * 96 + eo] + pS[2 * 96 + eo] + pS[3 * 96 + eo] + b2s;
            }
        }
    }
}

// ---------------- launcher ----------------
extern "C" void kernel_launch(void* const* d_in, const int* in_sizes, int n_in,
                              void* d_out, int out_size, void* d_ws, size_t ws_size,
                              hipStream_t stream) {
    const float* h   = (const float*)d_in[0];
    const int*   src = (const int*)d_in[1];
    const int*   dst = (const int*)d_in[2];
    const float* W0  = (const float*)d_in[3];
    const float* b0  = (const float*)d_in[4];
    const float* W1  = (const float*)d_in[5];
    const float* b1  = (const float*)d_in[6];
    const float* W2  = (const float*)d_in[7];
    const float* b2  = (const float*)d_in[8];
    const float* g0  = (const float*)d_in[9];
    const float* be0 = (const float*)d_in[10];
    const float* g1  = (const float*)d_in[11];
    const float* be1 = (const float*)d_in[12];
    const float* g2  = (const float*)d_in[13];
    const float* be2 = (const float*)d_in[14];
    const float* m0  = (const float*)d_in[15];
    const float* v0  = (const float*)d_in[16];
    const float* m1  = (const float*)d_in[17];
    const float* v1  = (const float*)d_in[18];
    const float* m2  = (const float*)d_in[19];
    const float* v2  = (const float*)d_in[20];
    float* out = (float*)d_out;

    const int hsz = in_sizes[0];          // N*128
    const int E   = in_sizes[1];

    char* ws = (char*)d_ws;
    size_t off = (size_t)hsz * 2;         // hb bytes
    off = (off + 255) & ~(size_t)255;
    unsigned short* hb   = (unsigned short*)ws;
    unsigned short* W0sw = (unsigned short*)(ws + off);  off += 65536;
    unsigned short* W1sw = (unsigned short*)(ws + off);  off += 32768;
    float* b0f = (float*)(ws + off);  off += 512;
    float* b1f = (float*)(ws + off);  off += 512;
    float* w2f = (float*)(ws + off);  off += 512;
    float* b2f = (float*)(ws + off);  off += 16;

    int n4   = hsz / 4;
    int nCvt = (n4 + 255) / 256;
    int prepBlocks = nCvt + 128 + 64 + 128;
    k_prep<<<prepBlocks, 256, 0, stream>>>(h, hb, n4, nCvt,
                                           W0, b0, W1, b1, W2, b2,
                                           g0, be0, m0, v0, g1, be1, m1, v1,
                                           g2, be2, m2, v2,
                                           W0sw, W1sw, b0f, b1f, w2f, b2f);

    int nGroups = (E + 95) / 96;
    int nBlocks = nGroups < 512 ? nGroups : 512;   // 2 blocks/CU (LDS 72 KB)
    k_main<<<nBlocks, 256, 0, stream>>>(src, dst, hb, W0sw, W1sw,
                                        b0f, b1f, w2f, b2f, out, E, nGroups);
}

// Round 9
// 146.232 us; speedup vs baseline: 1.0194x; 1.0194x over previous
//
#include <hip/hip_runtime.h>
#include <hip/hip_bf16.h>

#define BN_EPS 1e-5f
#define MG 3                 // 16-edge tiles per group
#define GEDGES 48            // edges per group

typedef short bf16x8 __attribute__((ext_vector_type(8)));
typedef float f32x4  __attribute__((ext_vector_type(4)));

static __device__ __forceinline__ unsigned short f2bf(float f) {
    union { float f; unsigned int u; } v; v.f = f;
    unsigned int u = v.u;
    unsigned int r = (u + 0x7FFFu + ((u >> 16) & 1u)) >> 16;   // RNE
    return (unsigned short)r;
}

static __device__ __forceinline__ unsigned short f2bf_hw(float f) {
    __hip_bfloat16 b = __float2bfloat16(f);
    union { __hip_bfloat16 b; unsigned short u; } v; v.b = b;
    return v.u;
}

// ---------------- fused prep kernel (unchanged) ----------------
__global__ __launch_bounds__(256) void k_prep(
        const float* __restrict__ h, unsigned short* __restrict__ hb, int n4, int nCvt,
        const float* __restrict__ W0, const float* __restrict__ b0,
        const float* __restrict__ W1, const float* __restrict__ b1,
        const float* __restrict__ W2, const float* __restrict__ b2,
        const float* __restrict__ g0, const float* __restrict__ be0,
        const float* __restrict__ m0, const float* __restrict__ v0,
        const float* __restrict__ g1, const float* __restrict__ be1,
        const float* __restrict__ m1, const float* __restrict__ v1,
        const float* __restrict__ g2, const float* __restrict__ be2,
        const float* __restrict__ m2, const float* __restrict__ v2,
        unsigned short* __restrict__ W0sw, unsigned short* __restrict__ W1sw,
        float* __restrict__ b0f, float* __restrict__ b1f,
        float* __restrict__ w2f, float* __restrict__ b2f) {
    const int b = blockIdx.x;
    const int tid = threadIdx.x;

    if (b < nCvt) {                       // ---- h -> bf16 ----
        int i = b * 256 + tid;
        if (i < n4) {
            float4 f = ((const float4*)h)[i];
            ushort4 o;
            o.x = f2bf(f.x); o.y = f2bf(f.y); o.z = f2bf(f.z); o.w = f2bf(f.w);
            ((ushort4*)hb)[i] = o;
        }
        return;
    }
    int br = b - nCvt;
    if (br < 128) {                        // ---- W0sw ----
        int t = br * 256 + tid;
        int j = t & 7, lane = (t >> 3) & 63, nt = (t >> 9) & 7, kb = t >> 12;
        int k = kb * 32 + (lane >> 4) * 8 + j;
        int n = nt * 16 + (lane & 15);
        float s = g0[k] * rsqrtf(v0[k] + BN_EPS);
        W0sw[t] = f2bf(W0[n * 256 + k] * s);
        return;
    }
    br -= 128;
    if (br < 64) {                         // ---- W1sw ----
        int t = br * 256 + tid;
        int j = t & 7, lane = (t >> 3) & 63, nt = (t >> 9) & 7, kb = t >> 12;
        int k = kb * 32 + (lane >> 4) * 8 + j;
        int n = nt * 16 + (lane & 15);
        float s = g1[k] * rsqrtf(v1[k] + BN_EPS);
        W1sw[t] = f2bf(W1[n * 128 + k] * s);
        return;
    }
    br -= 64;
    {                                      // ---- folded biases (row = br) ----
        if (tid >= 64) return;
        const int i = br, lane = tid;
        float s0 = 0.f;
#pragma unroll
        for (int c = 0; c < 4; c++) {
            int k = c * 64 + lane;
            float sc = g0[k] * rsqrtf(v0[k] + BN_EPS);
            s0 += W0[i * 256 + k] * (be0[k] - m0[k] * sc);
        }
        float s1 = 0.f;
#pragma unroll
        for (int c = 0; c < 2; c++) {
            int k = c * 64 + lane;
            float sc = g1[k] * rsqrtf(v1[k] + BN_EPS);
            s1 += W1[i * 128 + k] * (be1[k] - m1[k] * sc);
        }
        float s2 = 0.f;
        if (i == 0) {
#pragma unroll
            for (int c = 0; c < 2; c++) {
                int k = c * 64 + lane;
                float sc = g2[k] * rsqrtf(v2[k] + BN_EPS);
                s2 += W2[k] * (be2[k] - m2[k] * sc);
            }
        }
#pragma unroll
        for (int off = 1; off < 64; off <<= 1) {
            s0 += __shfl_xor(s0, off);
            s1 += __shfl_xor(s1, off);
            s2 += __shfl_xor(s2, off);
        }
        if (lane == 0) {
            b0f[i] = b0[i] + s0;
            b1f[i] = b1[i] + s1;
            w2f[i] = W2[i] * (g2[i] * rsqrtf(v2[i] + BN_EPS));
            if (i == 0) b2f[0] = b2[0] + s2;
        }
    }
}

// DMA gather of one group's A tiles. Unit = (chunk g, half); 6 units over 4 waves:
// waves 0,1: both halves of chunk g=wave; wave 2: (g=2, S-half); wave 3: (g=2, D-half).
static __device__ __forceinline__ void dma_issue(
        unsigned short* AbufBase, const unsigned short* __restrict__ hb,
        int wave, int lane, int quad, int rowS, int rowD) {
    const int gIdx = (wave < 2) ? wave : 2;
    const int h0 = (wave == 3) ? 1 : 0;
    const int h1 = (wave < 2) ? 1 : h0;
    for (int half = h0; half <= h1; half++) {
        int row = half ? rowD : rowS;
#pragma unroll
        for (int kb4 = 0; kb4 < 4; kb4++) {
            const unsigned short* gp = hb + (size_t)row * 128 + kb4 * 32 + quad * 8;
            unsigned short* lp = AbufBase + ((gIdx * 2 + half) * 4 + kb4) * 512 + lane * 8;
            __builtin_amdgcn_global_load_lds(
                (const __attribute__((address_space(1))) void*)gp,
                (__attribute__((address_space(3))) void*)lp, 16, 0, 0);
        }
    }
}

// ---------------- main kernel: single-barrier cross-group pipeline ----------------
// iter t: [one barrier] -> store out(G_{t-2}) -> issue DMA(G_{t+1}) -> prefetch
// indices(G_{t+2}) -> stage0(G_t) -> stage1+2(G_{t-1}).
// stage0(t) and stage1(t-1) are INDEPENDENT (different groups/buffers) -> the
// scheduler can interleave their MFMAs and ds_reads; the barrier no longer sits
// inside a data-dependency chain. Abuf/x1S/pS all double-buffered (73.5 KB LDS,
// 2 blocks/CU). Weights persistent in regs (n-split, wave w owns n=[32w,32w+32)).
__global__ __launch_bounds__(256, 2) void k_main(
        const int* __restrict__ src, const int* __restrict__ dst,
        const unsigned short* __restrict__ hb,
        const unsigned short* __restrict__ W0sw, const unsigned short* __restrict__ W1sw,
        const float* __restrict__ b0f, const float* __restrict__ b1f,
        const float* __restrict__ w2f, const float* __restrict__ b2fp,
        float* __restrict__ out, int E, int nGroups) {
    __shared__ __align__(16) unsigned short Abuf[2][MG * 2 * 4 * 64 * 8]; // 2 x 24 KB
    __shared__ __align__(16) unsigned short x1S[2][MG][4][64][8];         // 2 x 12 KB
    __shared__ float pS[2][4][GEDGES];                                    // 1.5 KB

    const int tid  = threadIdx.x;
    const int wave = tid >> 6;
    const int lane = tid & 63;
    const int quad = lane >> 4;
    const int m    = lane & 15;

    // ---- persistent weight fragments (nt = 2*wave + hh) ----
    bf16x8 B0[8][2], B1[4][2];
#pragma unroll
    for (int kb = 0; kb < 8; kb++)
#pragma unroll
        for (int hh = 0; hh < 2; hh++)
            B0[kb][hh] = *(const bf16x8*)(W0sw + ((kb * 8 + (wave * 2 + hh)) * 64 + lane) * 8);
#pragma unroll
    for (int kb = 0; kb < 4; kb++)
#pragma unroll
        for (int hh = 0; hh < 2; hh++)
            B1[kb][hh] = *(const bf16x8*)(W1sw + ((kb * 8 + (wave * 2 + hh)) * 64 + lane) * 8);

    float b0v[2], b1v[2], w2v[2];
#pragma unroll
    for (int hh = 0; hh < 2; hh++) {
        int n = (wave * 2 + hh) * 16 + m;
        b0v[hh] = b0f[n];
        b1v[hh] = b1f[n];
        w2v[hh] = w2f[n];
    }
    const float b2s = *b2fp;
    const int stride = gridDim.x;
    const int gIdx = (wave < 2) ? wave : 2;   // chunk whose rows this wave loads

    int gi = blockIdx.x;
    int p = 0;
    int eM1 = -1, eM2 = -1;     // eBase of groups t-1, t-2
    int rNS, rND;               // rows for the NEXT group's DMA

    // ---- prologue: DMA(G_first) into Abuf[0]; preload rows(G_first+stride) ----
    {
        int eb = gi * GEDGES;
        int e = eb + gIdx * 16 + m; if (e >= E) e = E - 1;
        int rs = src[e], rd = dst[e];
        dma_issue(&Abuf[0][0], hb, wave, lane, quad, rs, rd);
        int gN = gi + stride;
        int ebN = (gN < nGroups ? gN : gi) * GEDGES;
        int eN = ebN + gIdx * 16 + m; if (eN >= E) eN = E - 1;
        rNS = src[eN]; rND = dst[eN];
    }

    for (; gi < nGroups; gi += stride, p ^= 1) {
        __syncthreads();   // drains own DMA(G_t) + row loads; pS/x1S cross-wave visible

        // ---- store out(G_{t-2}) from pS[p^1] ----
        if (eM2 >= 0 && wave == 0 && lane < GEDGES) {
            int e = eM2 + lane;
            if (e < E)
                out[e] = pS[p ^ 1][0][lane] + pS[p ^ 1][1][lane] +
                         pS[p ^ 1][2][lane] + pS[p ^ 1][3][lane] + b2s;
        }

        // ---- issue DMA(G_{t+1}) into Abuf[p^1] ----
        if (gi + stride < nGroups)
            dma_issue(&Abuf[p ^ 1][0], hb, wave, lane, quad, rNS, rND);

        // ---- prefetch rows(G_{t+2}) ----
        {
            int g2i = gi + 2 * stride;
            int eb2 = (g2i < nGroups ? g2i : gi) * GEDGES;
            int e2 = eb2 + gIdx * 16 + m; if (e2 >= E) e2 = E - 1;
            rNS = src[e2]; rND = dst[e2];
        }

        // ---- stage 0 (G_t): Abuf[p] -> acc0 -> x1S[p] ----
        f32x4 acc0[MG][2];
#pragma unroll
        for (int g = 0; g < MG; g++)
#pragma unroll
            for (int hh = 0; hh < 2; hh++) acc0[g][hh] = (f32x4){0.f, 0.f, 0.f, 0.f};

#pragma unroll
        for (int kb = 0; kb < 8; kb++) {
            bf16x8 a[MG];
#pragma unroll
            for (int g = 0; g < MG; g++)
                a[g] = *(const bf16x8*)(&Abuf[p][((g * 2 + (kb >> 2)) * 4 + (kb & 3)) * 512 + lane * 8]);
#pragma unroll
            for (int hh = 0; hh < 2; hh++)
#pragma unroll
                for (int g = 0; g < MG; g++)
                    acc0[g][hh] = __builtin_amdgcn_mfma_f32_16x16x32_bf16(a[g], B0[kb][hh], acc0[g][hh], 0, 0, 0);
        }
#pragma unroll
        for (int g = 0; g < MG; g++) {
#pragma unroll
            for (int hh = 0; hh < 2; hh++) {
                int qp = (hh << 1) | (m >> 3);
                int j  = m & 7;
#pragma unroll
                for (int r = 0; r < 4; r++) {
                    float v = acc0[g][hh][r] + b0v[hh];
                    v = v > 0.f ? v : 0.f;
                    x1S[p][g][wave][qp * 16 + quad * 4 + r][j] = f2bf_hw(v);
                }
            }
        }

        // ---- stage 1+2 (G_{t-1}): x1S[p^1] -> acc1 -> partials -> pS[p] ----
        if (eM1 >= 0) {
            f32x4 acc1[MG][2];
#pragma unroll
            for (int g = 0; g < MG; g++)
#pragma unroll
                for (int hh = 0; hh < 2; hh++) acc1[g][hh] = (f32x4){0.f, 0.f, 0.f, 0.f};

#pragma unroll
            for (int kb = 0; kb < 4; kb++) {
                bf16x8 a[MG];
#pragma unroll
                for (int g = 0; g < MG; g++)
                    a[g] = *(const bf16x8*)&x1S[p ^ 1][g][kb][lane][0];
#pragma unroll
                for (int hh = 0; hh < 2; hh++)
#pragma unroll
                    for (int g = 0; g < MG; g++)
                        acc1[g][hh] = __builtin_amdgcn_mfma_f32_16x16x32_bf16(a[g], B1[kb][hh], acc1[g][hh], 0, 0, 0);
            }
#pragma unroll
            for (int g = 0; g < MG; g++) {
                float s[4] = {0.f, 0.f, 0.f, 0.f};
#pragma unroll
                for (int hh = 0; hh < 2; hh++)
#pragma unroll
                    for (int r = 0; r < 4; r++) {
                        float v = acc1[g][hh][r] + b1v[hh];
                        v = v > 0.f ? v : 0.f;
                        s[r] += v * w2v[hh];
                    }
#pragma unroll
                for (int off = 1; off < 16; off <<= 1)
#pragma unroll
                    for (int r = 0; r < 4; r++) s[r] += __shfl_xor(s[r], off, 16);
                if (m == 0) {
#pragma unroll
                    for (int r = 0; r < 4; r++)
                        pS[p][wave][g * 16 + quad * 4 + r] = s[r];
                }
            }
        }

        eM2 = eM1;
        eM1 = gi * GEDGES;
    }

    // ---- drain: store(G_{L-1}); stage1+2(G_L); store(G_L) ----
    __syncthreads();
    if (eM2 >= 0 && wave == 0 && lane < GEDGES) {
        int e = eM2 + lane;
        if (e < E)
            out[e] = pS[p ^ 1][0][lane] + pS[p ^ 1][1][lane] +
                     pS[p ^ 1][2][lane] + pS[p ^ 1][3][lane] + b2s;
    }
    if (eM1 >= 0) {
        f32x4 acc1[MG][2];
#pragma unroll
        for (int g = 0; g < MG; g++)
#pragma unroll
            for (int hh = 0; hh < 2; hh++) acc1[g][hh] = (f32x4){0.f, 0.f, 0.f, 0.f};
#pragma unroll
        for (int kb = 0; kb < 4; kb++) {
            bf16x8 a[MG];
#pragma unroll
            for (int g = 0; g < MG; g++)
                a[g] = *(const bf16x8*)&x1S[p ^ 1][g][kb][lane][0];
#pragma unroll
            for (int hh = 0; hh < 2; hh++)
#pragma unroll
                for (int g = 0; g < MG; g++)
                    acc1[g][hh] = __builtin_amdgcn_mfma_f32_16x16x32_bf16(a[g], B1[kb][hh], acc1[g][hh], 0, 0, 0);
        }
#pragma unroll
        for (int g = 0; g < MG; g++) {
            float s[4] = {0.f, 0.f, 0.f, 0.f};
#pragma unroll
            for (int hh = 0; hh < 2; hh++)
#pragma unroll
                for (int r = 0; r < 4; r++) {
                    float v = acc1[g][hh][r] + b1v[hh];
                    v = v > 0.f ? v : 0.f;
                    s[r] += v * w2v[hh];
                }
#pragma unroll
            for (int off = 1; off < 16; off <<= 1)
#pragma unroll
                for (int r = 0; r < 4; r++) s[r] += __shfl_xor(s[r], off, 16);
            if (m == 0) {
#pragma unroll
                for (int r = 0; r < 4; r++)
                    pS[p][wave][g * 16 + quad * 4 + r] = s[r];
            }
        }
    }
    __syncthreads();
    if (eM1 >= 0 && wave == 0 && lane < GEDGES) {
        int e = eM1 + lane;
        if (e < E)
            out[e] = pS[p][0][lane] + pS[p][1][lane] +
                     pS[p][2][lane] + pS[p][3][lane] + b2s;
    }
}

// ---------------- launcher ----------------
extern "C" void kernel_launch(void* const* d_in, const int* in_sizes, int n_in,
                              void* d_out, int out_size, void* d_ws, size_t ws_size,
                              hipStream_t stream) {
    const float* h   = (const float*)d_in[0];
    const int*   src = (const int*)d_in[1];
    const int*   dst = (const int*)d_in[2];
    const float* W0  = (const float*)d_in[3];
    const float* b0  = (const float*)d_in[4];
    const float* W1  = (const float*)d_in[5];
    const float* b1  = (const float*)d_in[6];
    const float* W2  = (const float*)d_in[7];
    const float* b2  = (const float*)d_in[8];
    const float* g0  = (const float*)d_in[9];
    const float* be0 = (const float*)d_in[10];
    const float* g1  = (const float*)d_in[11];
    const float* be1 = (const float*)d_in[12];
    const float* g2  = (const float*)d_in[13];
    const float* be2 = (const float*)d_in[14];
    const float* m0  = (const float*)d_in[15];
    const float* v0  = (const float*)d_in[16];
    const float* m1  = (const float*)d_in[17];
    const float* v1  = (const float*)d_in[18];
    const float* m2  = (const float*)d_in[19];
    const float* v2  = (const float*)d_in[20];
    float* out = (float*)d_out;

    const int hsz = in_sizes[0];          // N*128
    const int E   = in_sizes[1];

    char* ws = (char*)d_ws;
    size_t off = (size_t)hsz * 2;         // hb bytes
    off = (off + 255) & ~(size_t)255;
    unsigned short* hb   = (unsigned short*)ws;
    unsigned short* W0sw = (unsigned short*)(ws + off);  off += 65536;
    unsigned short* W1sw = (unsigned short*)(ws + off);  off += 32768;
    float* b0f = (float*)(ws + off);  off += 512;
    float* b1f = (float*)(ws + off);  off += 512;
    float* w2f = (float*)(ws + off);  off += 512;
    float* b2f = (float*)(ws + off);  off += 16;

    int n4   = hsz / 4;
    int nCvt = (n4 + 255) / 256;
    int prepBlocks = nCvt + 128 + 64 + 128;
    k_prep<<<prepBlocks, 256, 0, stream>>>(h, hb, n4, nCvt,
                                           W0, b0, W1, b1, W2, b2,
                                           g0, be0, m0, v0, g1, be1, m1, v1,
                                           g2, be2, m2, v2,
                                           W0sw, W1sw, b0f, b1f, w2f, b2f);

    int nGroups = (E + GEDGES - 1) / GEDGES;
    int nBlocks = nGroups < 512 ? nGroups : 512;   // 2 blocks/CU (LDS 73.5 KB)
    k_main<<<nBlocks, 256, 0, stream>>>(src, dst, hb, W0sw, W1sw,
                                        b0f, b1f, w2f, b2f, out, E, nGroups);
}

// Round 10
// 140.280 us; speedup vs baseline: 1.0626x; 1.0424x over previous
//
#include <hip/hip_runtime.h>
#include <hip/hip_bf16.h>

#define BN_EPS 1e-5f
#define MG 2                 // 16-edge tiles per group
#define GEDGES 32            // edges per group

typedef short bf16x8 __attribute__((ext_vector_type(8)));
typedef float f32x4  __attribute__((ext_vector_type(4)));

static __device__ __forceinline__ unsigned short f2bf(float f) {
    union { float f; unsigned int u; } v; v.f = f;
    unsigned int u = v.u;
    unsigned int r = (u + 0x7FFFu + ((u >> 16) & 1u)) >> 16;   // RNE
    return (unsigned short)r;
}

static __device__ __forceinline__ unsigned short f2bf_hw(float f) {
    __hip_bfloat16 b = __float2bfloat16(f);
    union { __hip_bfloat16 b; unsigned short u; } v; v.b = b;
    return v.u;
}

// ---------------- fused prep kernel (unchanged) ----------------
__global__ __launch_bounds__(256) void k_prep(
        const float* __restrict__ h, unsigned short* __restrict__ hb, int n4, int nCvt,
        const float* __restrict__ W0, const float* __restrict__ b0,
        const float* __restrict__ W1, const float* __restrict__ b1,
        const float* __restrict__ W2, const float* __restrict__ b2,
        const float* __restrict__ g0, const float* __restrict__ be0,
        const float* __restrict__ m0, const float* __restrict__ v0,
        const float* __restrict__ g1, const float* __restrict__ be1,
        const float* __restrict__ m1, const float* __restrict__ v1,
        const float* __restrict__ g2, const float* __restrict__ be2,
        const float* __restrict__ m2, const float* __restrict__ v2,
        unsigned short* __restrict__ W0sw, unsigned short* __restrict__ W1sw,
        float* __restrict__ b0f, float* __restrict__ b1f,
        float* __restrict__ w2f, float* __restrict__ b2f) {
    const int b = blockIdx.x;
    const int tid = threadIdx.x;

    if (b < nCvt) {                       // ---- h -> bf16 ----
        int i = b * 256 + tid;
        if (i < n4) {
            float4 f = ((const float4*)h)[i];
            ushort4 o;
            o.x = f2bf(f.x); o.y = f2bf(f.y); o.z = f2bf(f.z); o.w = f2bf(f.w);
            ((ushort4*)hb)[i] = o;
        }
        return;
    }
    int br = b - nCvt;
    if (br < 128) {                        // ---- W0sw ----
        int t = br * 256 + tid;
        int j = t & 7, lane = (t >> 3) & 63, nt = (t >> 9) & 7, kb = t >> 12;
        int k = kb * 32 + (lane >> 4) * 8 + j;
        int n = nt * 16 + (lane & 15);
        float s = g0[k] * rsqrtf(v0[k] + BN_EPS);
        W0sw[t] = f2bf(W0[n * 256 + k] * s);
        return;
    }
    br -= 128;
    if (br < 64) {                         // ---- W1sw ----
        int t = br * 256 + tid;
        int j = t & 7, lane = (t >> 3) & 63, nt = (t >> 9) & 7, kb = t >> 12;
        int k = kb * 32 + (lane >> 4) * 8 + j;
        int n = nt * 16 + (lane & 15);
        float s = g1[k] * rsqrtf(v1[k] + BN_EPS);
        W1sw[t] = f2bf(W1[n * 128 + k] * s);
        return;
    }
    br -= 64;
    {                                      // ---- folded biases (row = br) ----
        if (tid >= 64) return;
        const int i = br, lane = tid;
        float s0 = 0.f;
#pragma unroll
        for (int c = 0; c < 4; c++) {
            int k = c * 64 + lane;
            float sc = g0[k] * rsqrtf(v0[k] + BN_EPS);
            s0 += W0[i * 256 + k] * (be0[k] - m0[k] * sc);
        }
        float s1 = 0.f;
#pragma unroll
        for (int c = 0; c < 2; c++) {
            int k = c * 64 + lane;
            float sc = g1[k] * rsqrtf(v1[k] + BN_EPS);
            s1 += W1[i * 128 + k] * (be1[k] - m1[k] * sc);
        }
        float s2 = 0.f;
        if (i == 0) {
#pragma unroll
            for (int c = 0; c < 2; c++) {
                int k = c * 64 + lane;
                float sc = g2[k] * rsqrtf(v2[k] + BN_EPS);
                s2 += W2[k] * (be2[k] - m2[k] * sc);
            }
        }
#pragma unroll
        for (int off = 1; off < 64; off <<= 1) {
            s0 += __shfl_xor(s0, off);
            s1 += __shfl_xor(s1, off);
            s2 += __shfl_xor(s2, off);
        }
        if (lane == 0) {
            b0f[i] = b0[i] + s0;
            b1f[i] = b1[i] + s1;
            w2f[i] = W2[i] * (g2[i] * rsqrtf(v2[i] + BN_EPS));
            if (i == 0) b2f[0] = b2[0] + s2;
        }
    }
}

// DMA gather, MG=2: 4 units (chunk g, half) over 4 waves: wave w -> (g=w>>1, half=w&1).
static __device__ __forceinline__ void dma_issue(
        unsigned short* AbufBase, const unsigned short* __restrict__ hb,
        int gOwn, int halfOwn, int lane, int quad, int row) {
#pragma unroll
    for (int kb4 = 0; kb4 < 4; kb4++) {
        const unsigned short* gp = hb + (size_t)row * 128 + kb4 * 32 + quad * 8;
        unsigned short* lp = AbufBase + ((gOwn * 2 + halfOwn) * 4 + kb4) * 512 + lane * 8;
        __builtin_amdgcn_global_load_lds(
            (const __attribute__((address_space(1))) void*)gp,
            (__attribute__((address_space(3))) void*)lp, 16, 0, 0);
    }
}

// ---------------- main kernel: MG=2, single-barrier pipeline, 3 blocks/CU ----------------
// iter t: [one barrier] -> store out(G_{t-2}) -> issue DMA(G_{t+1}) -> load rows(G_{t+2})
// -> stage0(G_t) -> stage1+2(G_{t-1}).  Working set slimmed (acc 16+16, disjoint
// liveness) so the (256,3) cap fits WITHOUT spill (R6/R7 lesson: MG=4 ~190 regs
// spills at the 170 cap). 3 independent blocks/CU -> cross-phase pipe overlap.
__global__ __launch_bounds__(256, 3) void k_main(
        const int* __restrict__ src, const int* __restrict__ dst,
        const unsigned short* __restrict__ hb,
        const unsigned short* __restrict__ W0sw, const unsigned short* __restrict__ W1sw,
        const float* __restrict__ b0f, const float* __restrict__ b1f,
        const float* __restrict__ w2f, const float* __restrict__ b2fp,
        float* __restrict__ out, int E, int nGroups) {
    __shared__ __align__(16) unsigned short Abuf[2][MG * 2 * 4 * 64 * 8]; // 2 x 16 KB
    __shared__ __align__(16) unsigned short x1S[2][MG][4][64][8];         // 2 x 8 KB
    __shared__ float pS[2][4][GEDGES];                                    // 1 KB

    const int tid  = threadIdx.x;
    const int wave = tid >> 6;
    const int lane = tid & 63;
    const int quad = lane >> 4;
    const int m    = lane & 15;

    // ---- persistent weight fragments (nt = 2*wave + hh) ----
    bf16x8 B0[8][2], B1[4][2];
#pragma unroll
    for (int kb = 0; kb < 8; kb++)
#pragma unroll
        for (int hh = 0; hh < 2; hh++)
            B0[kb][hh] = *(const bf16x8*)(W0sw + ((kb * 8 + (wave * 2 + hh)) * 64 + lane) * 8);
#pragma unroll
    for (int kb = 0; kb < 4; kb++)
#pragma unroll
        for (int hh = 0; hh < 2; hh++)
            B1[kb][hh] = *(const bf16x8*)(W1sw + ((kb * 8 + (wave * 2 + hh)) * 64 + lane) * 8);

    float b0v[2], b1v[2], w2v[2];
#pragma unroll
    for (int hh = 0; hh < 2; hh++) {
        int n = (wave * 2 + hh) * 16 + m;
        b0v[hh] = b0f[n];
        b1v[hh] = b1f[n];
        w2v[hh] = w2f[n];
    }
    const float b2s = *b2fp;
    const int stride = gridDim.x;

    // DMA ownership: wave w loads (chunk gOwn = w>>1, half = w&1)
    const int gOwn = wave >> 1;
    const int halfOwn = wave & 1;
    const int* __restrict__ idxP = halfOwn ? dst : src;

    int gi = blockIdx.x;
    int p = 0;
    int eM1 = -1, eM2 = -1;     // eBase of groups t-1, t-2
    int rN;                     // row for the NEXT group's DMA (this wave's unit)

    // ---- prologue: DMA(G_first) into Abuf[0]; preload row(G_first+stride) ----
    {
        int e = gi * GEDGES + gOwn * 16 + m; if (e >= E) e = E - 1;
        int r0 = idxP[e];
        dma_issue(&Abuf[0][0], hb, gOwn, halfOwn, lane, quad, r0);
        int gN = gi + stride;
        int ebN = (gN < nGroups ? gN : gi) * GEDGES;
        int eN = ebN + gOwn * 16 + m; if (eN >= E) eN = E - 1;
        rN = idxP[eN];
    }

    for (; gi < nGroups; gi += stride, p ^= 1) {
        __syncthreads();   // drains own DMA(G_t) + row load; pS/x1S cross-wave visible

        // ---- store out(G_{t-2}) from pS[p^1] ----
        if (eM2 >= 0 && wave == 0 && lane < GEDGES) {
            int e = eM2 + lane;
            if (e < E)
                out[e] = pS[p ^ 1][0][lane] + pS[p ^ 1][1][lane] +
                         pS[p ^ 1][2][lane] + pS[p ^ 1][3][lane] + b2s;
        }

        // ---- issue DMA(G_{t+1}) into Abuf[p^1] ----
        if (gi + stride < nGroups)
            dma_issue(&Abuf[p ^ 1][0], hb, gOwn, halfOwn, lane, quad, rN);

        // ---- load row(G_{t+2}) ----
        {
            int g2i = gi + 2 * stride;
            int eb2 = (g2i < nGroups ? g2i : gi) * GEDGES;
            int e2 = eb2 + gOwn * 16 + m; if (e2 >= E) e2 = E - 1;
            rN = idxP[e2];
        }

        // ---- stage 0 (G_t): Abuf[p] -> acc0 -> x1S[p] ----
        {
            f32x4 acc0[MG][2];
#pragma unroll
            for (int g = 0; g < MG; g++)
#pragma unroll
                for (int hh = 0; hh < 2; hh++) acc0[g][hh] = (f32x4){0.f, 0.f, 0.f, 0.f};

#pragma unroll
            for (int kb = 0; kb < 8; kb++) {
                bf16x8 a[MG];
#pragma unroll
                for (int g = 0; g < MG; g++)
                    a[g] = *(const bf16x8*)(&Abuf[p][((g * 2 + (kb >> 2)) * 4 + (kb & 3)) * 512 + lane * 8]);
#pragma unroll
                for (int hh = 0; hh < 2; hh++)
#pragma unroll
                    for (int g = 0; g < MG; g++)
                        acc0[g][hh] = __builtin_amdgcn_mfma_f32_16x16x32_bf16(a[g], B0[kb][hh], acc0[g][hh], 0, 0, 0);
            }
#pragma unroll
            for (int g = 0; g < MG; g++) {
#pragma unroll
                for (int hh = 0; hh < 2; hh++) {
                    int qp = (hh << 1) | (m >> 3);
                    int j  = m & 7;
#pragma unroll
                    for (int r = 0; r < 4; r++) {
                        float v = acc0[g][hh][r] + b0v[hh];
                        v = v > 0.f ? v : 0.f;
                        x1S[p][g][wave][qp * 16 + quad * 4 + r][j] = f2bf_hw(v);
                    }
                }
            }
        }

        // ---- stage 1+2 (G_{t-1}): x1S[p^1] -> acc1 -> partials -> pS[p] ----
        if (eM1 >= 0) {
            f32x4 acc1[MG][2];
#pragma unroll
            for (int g = 0; g < MG; g++)
#pragma unroll
                for (int hh = 0; hh < 2; hh++) acc1[g][hh] = (f32x4){0.f, 0.f, 0.f, 0.f};

#pragma unroll
            for (int kb = 0; kb < 4; kb++) {
                bf16x8 a[MG];
#pragma unroll
                for (int g = 0; g < MG; g++)
                    a[g] = *(const bf16x8*)&x1S[p ^ 1][g][kb][lane][0];
#pragma unroll
                for (int hh = 0; hh < 2; hh++)
#pragma unroll
                    for (int g = 0; g < MG; g++)
                        acc1[g][hh] = __builtin_amdgcn_mfma_f32_16x16x32_bf16(a[g], B1[kb][hh], acc1[g][hh], 0, 0, 0);
            }
#pragma unroll
            for (int g = 0; g < MG; g++) {
                float s[4] = {0.f, 0.f, 0.f, 0.f};
#pragma unroll
                for (int hh = 0; hh < 2; hh++)
#pragma unroll
                    for (int r = 0; r < 4; r++) {
                        float v = acc1[g][hh][r] + b1v[hh];
                        v = v > 0.f ? v : 0.f;
                        s[r] += v * w2v[hh];
                    }
#pragma unroll
                for (int off = 1; off < 16; off <<= 1)
#pragma unroll
                    for (int r = 0; r < 4; r++) s[r] += __shfl_xor(s[r], off, 16);
                if (m == 0) {
#pragma unroll
                    for (int r = 0; r < 4; r++)
                        pS[p][wave][g * 16 + quad * 4 + r] = s[r];
                }
            }
        }

        eM2 = eM1;
        eM1 = gi * GEDGES;
    }

    // ---- drain: store(G_{L-1}); stage1+2(G_L); store(G_L) ----
    __syncthreads();
    if (eM2 >= 0 && wave == 0 && lane < GEDGES) {
        int e = eM2 + lane;
        if (e < E)
            out[e] = pS[p ^ 1][0][lane] + pS[p ^ 1][1][lane] +
                     pS[p ^ 1][2][lane] + pS[p ^ 1][3][lane] + b2s;
    }
    if (eM1 >= 0) {
        f32x4 acc1[MG][2];
#pragma unroll
        for (int g = 0; g < MG; g++)
#pragma unroll
            for (int hh = 0; hh < 2; hh++) acc1[g][hh] = (f32x4){0.f, 0.f, 0.f, 0.f};
#pragma unroll
        for (int kb = 0; kb < 4; kb++) {
            bf16x8 a[MG];
#pragma unroll
            for (int g = 0; g < MG; g++)
                a[g] = *(const bf16x8*)&x1S[p ^ 1][g][kb][lane][0];
#pragma unroll
            for (int hh = 0; hh < 2; hh++)
#pragma unroll
                for (int g = 0; g < MG; g++)
                    acc1[g][hh] = __builtin_amdgcn_mfma_f32_16x16x32_bf16(a[g], B1[kb][hh], acc1[g][hh], 0, 0, 0);
        }
#pragma unroll
        for (int g = 0; g < MG; g++) {
            float s[4] = {0.f, 0.f, 0.f, 0.f};
#pragma unroll
            for (int hh = 0; hh < 2; hh++)
#pragma unroll
                for (int r = 0; r < 4; r++) {
                    float v = acc1[g][hh][r] + b1v[hh];
                    v = v > 0.f ? v : 0.f;
                    s[r] += v * w2v[hh];
                }
#pragma unroll
            for (int off = 1; off < 16; off <<= 1)
#pragma unroll
                for (int r = 0; r < 4; r++) s[r] += __shfl_xor(s[r], off, 16);
            if (m == 0) {
#pragma unroll
                for (int r = 0; r < 4; r++)
                    pS[p][wave][g * 16 + quad * 4 + r] = s[r];
            }
        }
    }
    __syncthreads();
    if (eM1 >= 0 && wave == 0 && lane < GEDGES) {
        int e = eM1 + lane;
        if (e < E)
            out[e] = pS[p][0][lane] + pS[p][1][lane] +
                     pS[p][2][lane] + pS[p][3][lane] + b2s;
    }
}

// ---------------- launcher ----------------
extern "C" void kernel_launch(void* const* d_in, const int* in_sizes, int n_in,
                              void* d_out, int out_size, void* d_ws, size_t ws_size,
                              hipStream_t stream) {
    const float* h   = (const float*)d_in[0];
    const int*   src = (const int*)d_in[1];
    const int*   dst = (const int*)d_in[2];
    const float* W0  = (const float*)d_in[3];
    const float* b0  = (const float*)d_in[4];
    const float* W1  = (const float*)d_in[5];
    const float* b1  = (const float*)d_in[6];
    const float* W2  = (const float*)d_in[7];
    const float* b2  = (const float*)d_in[8];
    const float* g0  = (const float*)d_in[9];
    const float* be0 = (const float*)d_in[10];
    const float* g1  = (const float*)d_in[11];
    const float* be1 = (const float*)d_in[12];
    const float* g2  = (const float*)d_in[13];
    const float* be2 = (const float*)d_in[14];
    const float* m0  = (const float*)d_in[15];
    const float* v0  = (const float*)d_in[16];
    const float* m1  = (const float*)d_in[17];
    const float* v1  = (const float*)d_in[18];
    const float* m2  = (const float*)d_in[19];
    const float* v2  = (const float*)d_in[20];
    float* out = (float*)d_out;

    const int hsz = in_sizes[0];          // N*128
    const int E   = in_sizes[1];

    char* ws = (char*)d_ws;
    size_t off = (size_t)hsz * 2;         // hb bytes
    off = (off + 255) & ~(size_t)255;
    unsigned short* hb   = (unsigned short*)ws;
    unsigned short* W0sw = (unsigned short*)(ws + off);  off += 65536;
    unsigned short* W1sw = (unsigned short*)(ws + off);  off += 32768;
    float* b0f = (float*)(ws + off);  off += 512;
    float* b1f = (float*)(ws + off);  off += 512;
    float* w2f = (float*)(ws + off);  off += 512;
    float* b2f = (float*)(ws + off);  off += 16;

    int n4   = hsz / 4;
    int nCvt = (n4 + 255) / 256;
    int prepBlocks = nCvt + 128 + 64 + 128;
    k_prep<<<prepBlocks, 256, 0, stream>>>(h, hb, n4, nCvt,
                                           W0, b0, W1, b1, W2, b2,
                                           g0, be0, m0, v0, g1, be1, m1, v1,
                                           g2, be2, m2, v2,
                                           W0sw, W1sw, b0f, b1f, w2f, b2f);

    int nGroups = (E + GEDGES - 1) / GEDGES;
    int nBlocks = nGroups < 768 ? nGroups : 768;   // 3 blocks/CU (LDS 49.25 KB, regs <=170)
    k_main<<<nBlocks, 256, 0, stream>>>(src, dst, hb, W0sw, W1sw,
                                        b0f, b1f, w2f, b2f, out, E, nGroups);
}